// Round 15
// baseline (12986.772 us; speedup 1.0000x reference)
//
#include <hip/hip_runtime.h>
#include <math.h>

#define HID   800
#define ALPH  20
#define SEQL  700
#define TWOH  1600

typedef _Float16 f16;
typedef _Float16 f16x8 __attribute__((ext_vector_type(8)));
typedef float    f32x4 __attribute__((ext_vector_type(4)));

__device__ __forceinline__ float sigm(float x) { return 1.0f / (1.0f + __expf(-x)); }
__device__ __forceinline__ float tanh_(float x) { return 1.0f - 2.0f / (1.0f + __expf(2.0f * x)); }

// x [B=32][L=700][42] f32  ->  xT [t][b][64] f16 (zero-padded 42->64)
__global__ __launch_bounds__(256) void transpose_x(const float* __restrict__ x,
                                                   f16* __restrict__ xT) {
    const int t = blockIdx.x;
    const int b = threadIdx.x >> 3;
    const int kc = (threadIdx.x & 7) * 8;
    #pragma unroll
    for (int e = 0; e < 8; ++e) {
        int k = kc + e;
        float v = (k < 42) ? x[((size_t)b * SEQL + t) * 42 + k] : 0.f;
        xT[(size_t)t * 2048 + b * 64 + k] = (f16)v;
    }
}

// ---------------------------------------------------------------------------
// Persistent LSTM layer, weight-stationary MFMA, fenceless L3-deposit sync
// (R13/R14 structure). h published via RETURNING u32 atomic_fetch_add into
// pre-zeroed fresh t-indexed addresses (performed at L3 when vmcnt drains);
// loop-top __syncthreads then arrival RMW; consumers poll counters and read
// fresh addresses with plain loads. No cache-maintenance fences anywhere.
// R15 edit vs R14 (ONE change): logits blocks are DETACHED from the barrier
// -- they never fetch_add (GSIZE 105->100 for L1); mains never wait on them.
// Their poll of the mains' counters still guarantees visibility (mains'
// top-of-loop syncthreads orders deposit-drain before arrival), and hh is
// t-indexed / never overwritten, so arbitrary logits lag is safe.
// 8 waves/block: (tile = wid>>2, kw = wid&3); tile = 16 rows (4j x 4gates
// interleaved) x 32 batch; TPB=2 tiles; 4-way K-split reduced in LDS.
// LAYER 0: 200 blocks (100/dir); A = x-proj (K=64), B = Whh (K=800).
// LAYER 1: 200 mains + 10 logits blocks; A = Wih1 (K=1600 cached h1 reads),
//          B = Whh (K=800 reads of hh deposits); logits blocks consume hh
//          one step behind, write-once per-dir f16.
// ---------------------------------------------------------------------------
template <int LAYER>
__global__ __launch_bounds__(512) void lstm_phase(
    const float* __restrict__ Wih_f, const float* __restrict__ Wih_r,
    const float* __restrict__ Whh_f, const float* __restrict__ Whh_r,
    const float* __restrict__ bias_f, const float* __restrict__ bias_r,
    const f16* __restrict__ xT,
    f16* __restrict__ h1,
    f16* __restrict__ hh,
    f16* __restrict__ logF, f16* __restrict__ logR,
    const float* __restrict__ Wlin,
    unsigned* __restrict__ bar)
{
    constexpr int TPB   = 2;
    constexpr int BPD   = 100;
    constexpr int NMAIN = 200;
    constexpr int MAXA  = (LAYER == 0) ? 2 : 13;
    constexpr int MAXB  = 7;
    constexpr int GSIZE = 100;          // mains only; logits blocks never arrive
    constexpr int SMAX  = (LAYER == 0) ? 699 : 700;

    __shared__ float lds_part[8][2][16][16];
    __shared__ float lds_pre[TPB][16][32];
    __shared__ float lds_c[TPB][4][32];
    __shared__ f16   lds_h[TPB * 4][32];

    const int bid = blockIdx.x, tid = threadIdx.x;
    const int lane = tid & 63, wid = tid >> 6;
    const bool is_main = (LAYER == 0) || (bid < NMAIN);

    int dir, tb = 0;
    if (is_main) { dir = bid / BPD; tb = bid % BPD; }
    else         { dir = (bid - NMAIN) / 5; }
    unsigned* grp   = bar + ((LAYER == 0 ? 0 : 2) + dir) * 512;
    unsigned* myctr = grp + (bid & 7) * 64;

    const int tile_sel = wid >> 2, kw = wid & 3;
    const int row_local = lane & 15;
    const int kg8 = (lane >> 4) * 8;

    int cntA, offA;
    if constexpr (LAYER == 0) { cntA = (kw == 0) ? 2 : 0; offA = 0; }
    else { cntA = (kw < 2) ? 13 : 12; offA = (kw < 2) ? kw * 13 : 26 + (kw - 2) * 12; }
    const int cntB = (kw == 0) ? 7 : 6;
    const int offB = (kw == 0) ? 0 : 7 + (kw - 1) * 6;

    f16x8 aregA[MAXA];
    f16x8 aregB[MAXB];
    float biasreg[2] = {0.f, 0.f};

    if (is_main) {
        const int gate = row_local >> 2, jl = row_local & 3;
        const int jtile = tb * TPB + tile_sel;
        const int grow = gate * HID + jtile * 4 + jl;
        const float* Wih = dir ? Wih_r : Wih_f;
        const float* Whh = dir ? Whh_r : Whh_f;

        #pragma unroll
        for (int fi = 0; fi < MAXA; ++fi) {
            f16x8 a{};
            if (fi < cntA) {
                int kf = offA + fi;
                if constexpr (LAYER == 0) {
                    int k0 = kf * 32 + kg8;
                    #pragma unroll
                    for (int e = 0; e < 8; ++e)
                        a[e] = (f16)((k0 + e < 42) ? Wih[(size_t)grow * 42 + k0 + e] : 0.f);
                } else {
                    const float* p = Wih + (size_t)grow * TWOH + kf * 32 + kg8;
                    #pragma unroll
                    for (int e = 0; e < 8; ++e) a[e] = (f16)p[e];
                }
            }
            aregA[fi] = a;
        }
        #pragma unroll
        for (int fi = 0; fi < MAXB; ++fi) {
            f16x8 a{};
            if (fi < cntB) {
                const float* p = Whh + (size_t)grow * HID + (offB + fi) * 32 + kg8;
                #pragma unroll
                for (int e = 0; e < 8; ++e) a[e] = (f16)p[e];
            }
            aregB[fi] = a;
        }
        const float* bias = dir ? bias_r : bias_f;
        #pragma unroll
        for (int i = 0; i < 2; ++i) {
            int idx = tid + i * 512;
            int row = (idx >> 5) & 15, tile = idx >> 9;
            biasreg[i] = bias[(row >> 2) * HID + (tb * TPB + tile) * 4 + (row & 3)];
        }
        if (tid < TPB * 128) {
            int tile = tid >> 7, jl_ = (tid >> 5) & 3, b = tid & 31;
            lds_c[tile][jl_][b] = 0.f;
        }
    }
    __syncthreads();

    for (int s = 0; s <= SMAX; ++s) {
        const int t = dir ? (SEQL - 1 - s) : s;
        const bool do_comp = is_main && (LAYER == 0 || s < SEQL);

        __syncthreads();   // vmcnt(0): returning deposits PERFORMED at L3 pre-signal
        if (is_main && tid == 0)
            __hip_atomic_fetch_add(myctr, 1u, __ATOMIC_RELAXED, __HIP_MEMORY_SCOPE_AGENT);

        // ---- overlapped with other blocks' arrival: input projection ----
        f32x4 acc2[2];
        #pragma unroll
        for (int bt = 0; bt < 2; ++bt) acc2[bt] = {0.f, 0.f, 0.f, 0.f};
        if (do_comp) {
            const f16* srcin = (LAYER == 0) ? (xT + (size_t)t * 2048)
                                            : (h1 + (size_t)t * 51200);
            #pragma unroll
            for (int bt = 0; bt < 2; ++bt) {
                const int bcol = bt * 16 + row_local;
                #pragma unroll
                for (int fi = 0; fi < MAXA; ++fi) {
                    if (fi < cntA) {
                        int kf = offA + fi;
                        const f16x8* p = (LAYER == 0)
                            ? (const f16x8*)(srcin + (size_t)bcol * 64 + kf * 32 + kg8)
                            : (const f16x8*)(srcin + (size_t)bcol * TWOH + kf * 32 + kg8);
                        acc2[bt] = __builtin_amdgcn_mfma_f32_16x16x32_f16(aregA[fi], *p, acc2[bt], 0, 0, 0);
                    }
                }
            }
        }

        {
            // poll: lanes 0-7 read the 8 sub-counter lines in parallel,
            // shfl-reduce + broadcast; loads below are control-dependent on c
            const unsigned tgt = (unsigned)GSIZE * (unsigned)(s + 1);
            unsigned c;
            for (;;) {
                unsigned v = 0;
                if (lane < 8)
                    v = __hip_atomic_load(grp + lane * 64, __ATOMIC_RELAXED, __HIP_MEMORY_SCOPE_AGENT);
                v += __shfl_xor(v, 1);
                v += __shfl_xor(v, 2);
                v += __shfl_xor(v, 4);
                c = __shfl(v, 0);
                if (c >= tgt) break;
                __builtin_amdgcn_s_sleep(1);
            }
            if (c == 0xFFFFFFFFu) return;   // never taken: pins loads after poll
            // no acquire fence: all communicated reads below hit FRESH addresses
        }

        // ---- recurrence + finalize ----
        if (do_comp) {
            if (s > 0) {
                const int tprev = dir ? t + 1 : t - 1;
                const f16* srcrec = (LAYER == 0)
                    ? (h1 + (size_t)tprev * 51200 + dir * HID)
                    : (hh + ((size_t)(tprev * 2 + dir) * 32) * 800);
                #pragma unroll
                for (int bt = 0; bt < 2; ++bt) {
                    const int bcol = bt * 16 + row_local;
                    #pragma unroll
                    for (int fi = 0; fi < MAXB; ++fi) {
                        if (fi < cntB) {
                            int kf = offB + fi;
                            const f16x8* p = (LAYER == 0)
                                ? (const f16x8*)(srcrec + (size_t)bcol * TWOH + kf * 32 + kg8)
                                : (const f16x8*)(srcrec + (size_t)bcol * HID + kf * 32 + kg8);
                            acc2[bt] = __builtin_amdgcn_mfma_f32_16x16x32_f16(aregB[fi], *p, acc2[bt], 0, 0, 0);
                        }
                    }
                }
            }
            #pragma unroll
            for (int bt = 0; bt < 2; ++bt)
                #pragma unroll
                for (int r = 0; r < 4; ++r)
                    lds_part[wid][bt][(lane >> 4) * 4 + r][row_local] = acc2[bt][r];
        }
        __syncthreads();
        if (do_comp) {
            #pragma unroll
            for (int i = 0; i < 2; ++i) {
                int idx = tid + i * 512;
                int b = idx & 31, row = (idx >> 5) & 15, tile = idx >> 9;
                float sum = biasreg[i];
                #pragma unroll
                for (int k2 = 0; k2 < 4; ++k2)
                    sum += lds_part[tile * 4 + k2][b >> 4][row][b & 15];
                lds_pre[tile][row][b] = sum;
            }
        }
        __syncthreads();
        if (do_comp && tid < TPB * 128) {
            int tile = tid >> 7, jl_ = (tid >> 5) & 3, b = tid & 31;
            float gi = sigm(lds_pre[tile][jl_][b]);
            float gf = sigm(lds_pre[tile][4 + jl_][b]);
            float gg = tanh_(lds_pre[tile][8 + jl_][b]);
            float go = sigm(lds_pre[tile][12 + jl_][b]);
            float c = gf * lds_c[tile][jl_][b] + gi * gg;
            lds_c[tile][jl_][b] = c;
            lds_h[tile * 4 + jl_][b] = (f16)(go * tanh_(c));
        }
        __syncthreads();
        if (do_comp && tid < 32) {
            union { f16x8 h; unsigned u[4]; } v;
            #pragma unroll
            for (int e = 0; e < 8; ++e) v.h[e] = lds_h[e][tid];
            f16* dst = (LAYER == 0)
                ? h1 + (size_t)t * 51200 + (size_t)tid * TWOH + dir * HID + tb * 8
                : hh + ((size_t)(t * 2 + dir) * 32 + tid) * 800 + tb * 8;
            unsigned* du = (unsigned*)dst;
            // RETURNING deposits: vmcnt tracks DATA RETURN = performed at L3.
            unsigned keep = 0;
            #pragma unroll
            for (int e = 0; e < 4; ++e)
                keep |= __hip_atomic_fetch_add(du + e, v.u[e], __ATOMIC_RELAXED, __HIP_MEMORY_SCOPE_AGENT);
            asm volatile("" : : "v"(keep));   // zero-cost keepalive (no instruction)
        }
        // logits blocks: consume hh one step behind; WRITE-ONCE per-dir f16
        if (LAYER == 1 && !is_main && s >= 1) {
            const int lb = bid - NMAIN;
            const int tL = dir ? (SEQL - s) : (s - 1);
            const int a = (lb % 5) * 4 + (tid >> 7);
            const int b = (tid >> 2) & 31;
            const int kc = tid & 3;
            const f16* hs = hh + ((size_t)(tL * 2 + dir) * 32 + b) * 800 + kc * 200;
            const float* wsrc = Wlin + (size_t)a * TWOH + dir * HID + kc * 200;
            float acc = 0.f;
            #pragma unroll
            for (int q = 0; q < 25; ++q) {
                f16x8 hv = ((const f16x8*)hs)[q];
                #pragma unroll
                for (int e = 0; e < 8; ++e) acc += (float)hv[e] * wsrc[q * 8 + e];
            }
            acc += __shfl_xor(acc, 1);
            acc += __shfl_xor(acc, 2);
            if (kc == 0) {
                f16* dst = dir ? logR : logF;
                dst[(size_t)tL * 640 + a * 32 + b] = (f16)acc;
            }
        }
    }
}

// softmax over batch (dim=1) per (l,a); prob-weighted sin/cos -> pts [m][2][32]
__global__ __launch_bounds__(64) void softmax_pts(
    const f16* __restrict__ logF, const f16* __restrict__ logR,
    const float* __restrict__ blin,
    const float* __restrict__ alpha, float* __restrict__ pts)
{
    const int l = blockIdx.x;
    const int tid = threadIdx.x;
    const int b = tid & 31;
    float sins[3] = {0.f, 0.f, 0.f}, coss[3] = {0.f, 0.f, 0.f};
    for (int a = 0; a < ALPH; ++a) {
        size_t idx = (size_t)l * 640 + (size_t)a * 32 + b;
        float v = (float)logF[idx] + (float)logR[idx] + blin[a];
        float m = v;
        #pragma unroll
        for (int d = 16; d >= 1; d >>= 1) m = fmaxf(m, __shfl_xor(m, d));
        float e = __expf(v - m);
        float ssum = e;
        #pragma unroll
        for (int d = 16; d >= 1; d >>= 1) ssum += __shfl_xor(ssum, d);
        float pv = e / ssum;
        #pragma unroll
        for (int d = 0; d < 3; ++d) {
            float ang = alpha[a * 3 + d];
            sins[d] += pv * sinf(ang);
            coss[d] += pv * cosf(ang);
        }
    }
    if (tid < 32) {
        const float blen[3] = {145.801f, 152.326f, 132.868f};
        const float bang[3] = {2.124f, 1.941f, 2.028f};
        #pragma unroll
        for (int d = 0; d < 3; ++d) {
            float pa = 3.14159265358979323846f - bang[d];
            float rsin = blen[d] * sinf(pa);
            float sv = sins[d], cv = coss[d];
            float den = sqrtf(sv * sv + cv * cv);
            float cs, sn;
            if (den > 0.f) { cs = cv / den; sn = sv / den; }
            else           { cs = 1.f;     sn = 0.f; }
            size_t m = (size_t)(3 * l + d);
            pts[m * 64 + b]      = cs * rsin;
            pts[m * 64 + 32 + b] = sn * rsin;
        }
    }
}

// NeRF chain: 32 independent batch chains in one wave.
__global__ __launch_bounds__(64) void coords_kernel(
    const float* __restrict__ pts, float* __restrict__ out)
{
    const int tid = threadIdx.x;
    const int b = tid & 31;
    float ax = -0.70710678118654752f, ay = 1.22474487139158905f, az = 0.f;
    float bx = -1.41421356237309505f, by = 0.f, bz = 0.f;
    float cx = 0.f, cy = 0.f, cz = 0.f;
    const float blen[3] = {145.801f, 152.326f, 132.868f};
    const float bang[3] = {2.124f, 1.941f, 2.028f};
    float rcos[3], rb[3];
    #pragma unroll
    for (int d = 0; d < 3; ++d) {
        rcos[d] = blen[d] * cosf(3.14159265358979323846f - bang[d]);
        rb[d] = 1.0f / blen[d];
    }
    int j = 0;
    for (int m = 0; m < 3 * SEQL; ++m) {
        float px = rcos[j];
        float py = pts[(size_t)m * 64 + b];
        float pz = pts[(size_t)m * 64 + 32 + b];
        float ux = cx - bx, uy = cy - by, uz = cz - bz;
        float inv = (m == 0) ? rsqrtf(ux * ux + uy * uy + uz * uz + 1e-12f)
                             : rb[(j + 2) % 3];
        float vx = bx - ax, vy = by - ay, vz = bz - az;
        float nx = vy * uz - vz * uy;
        float ny = vz * ux - vx * uz;
        float nz = vx * uy - vy * ux;
        float inv2 = rsqrtf(nx * nx + ny * ny + nz * nz + 1e-12f);
        nx *= inv2; ny *= inv2; nz *= inv2;
        float mx = ny * uz - nz * uy;
        float my = nz * ux - nx * uz;
        float mz = nx * uy - ny * ux;
        float sx = px * inv, sy = py * inv;
        float ox = cx + ux * sx + mx * sy + nx * pz;
        float oy = cy + uy * sx + my * sy + ny * pz;
        float oz = cz + uz * sx + mz * sy + nz * pz;
        if (tid < 32) {
            float* o = out + ((size_t)m * 32 + b) * 3;
            o[0] = ox; o[1] = oy; o[2] = oz;
        }
        ax = bx; ay = by; az = bz;
        bx = cx; by = cy; bz = cz;
        cx = ox; cy = oy; cz = oz;
        j = (j == 2) ? 0 : j + 1;
    }
}

// ---------------------------------------------------------------------------
extern "C" void kernel_launch(void* const* d_in, const int* in_sizes, int n_in,
                              void* d_out, int out_size, void* d_ws, size_t ws_size,
                              hipStream_t stream)
{
    const float* x     = (const float*)d_in[0];
    const float* Wih0f = (const float*)d_in[1];
    const float* Whh0f = (const float*)d_in[2];
    const float* b0f   = (const float*)d_in[3];
    const float* Wih0r = (const float*)d_in[4];
    const float* Whh0r = (const float*)d_in[5];
    const float* b0r   = (const float*)d_in[6];
    const float* Wih1f = (const float*)d_in[7];
    const float* Whh1f = (const float*)d_in[8];
    const float* b1f   = (const float*)d_in[9];
    const float* Wih1r = (const float*)d_in[10];
    const float* Whh1r = (const float*)d_in[11];
    const float* b1r   = (const float*)d_in[12];
    const float* Wlin  = (const float*)d_in[13];
    const float* blin  = (const float*)d_in[14];
    const float* alpha = (const float*)d_in[15];

    // ws: [bar 8KB][h1 71.68MB][hh 71.68MB][region 2.8672MB]
    // region: xT (L0 phase, dead after) aliased in L1 phase by:
    //   logF f16 @0 (896,000) | logR f16 @896,000 (896,000) |
    //   pts f32 @1,792,000 (537,600)   (total 2,329,600 <= 2,867,200)
    const size_t needFast = 8192ull + 71680000ull + 71680000ull + 2867200ull;  // 146,235,392
    if (ws_size < needFast) return;   // proven available (R10/R13/R14 ran)

    unsigned* bar = (unsigned*)d_ws;
    f16* h1 = (f16*)((char*)d_ws + 8192);
    f16* hh = (f16*)((char*)d_ws + 8192 + 71680000ull);
    char* region = (char*)d_ws + 8192 + 2ull * 71680000ull;
    f16*   xT     = (f16*)region;
    f16*   logF   = (f16*)region;
    f16*   logR   = (f16*)(region + 896000);
    float* pts    = (float*)(region + 1792000);

    hipMemsetAsync(bar, 0, 8192, stream);
    // zero h1+hh (contiguous): deposits assume old==0
    hipMemsetAsync(h1, 0, 2ull * 71680000ull, stream);
    transpose_x<<<SEQL, 256, 0, stream>>>(x, xT);
    lstm_phase<0><<<200, 512, 0, stream>>>(
        Wih0f, Wih0r, Whh0f, Whh0r, b0f, b0r,
        xT, h1, hh, logF, logR, Wlin, bar);
    lstm_phase<1><<<210, 512, 0, stream>>>(
        Wih1f, Wih1r, Whh1f, Whh1r, b1f, b1r,
        xT, h1, hh, logF, logR, Wlin, bar);
    softmax_pts<<<SEQL, 64, 0, stream>>>(logF, logR, blin, alpha, pts);
    coords_kernel<<<1, 64, 0, stream>>>(pts, (float*)d_out);
}

// Round 16
// 12446.422 us; speedup vs baseline: 1.0434x; 1.0434x over previous
//
#include <hip/hip_runtime.h>
#include <math.h>

#define HID   800
#define ALPH  20
#define SEQL  700
#define TWOH  1600

typedef _Float16 f16;
typedef _Float16 f16x8 __attribute__((ext_vector_type(8)));
typedef float    f32x4 __attribute__((ext_vector_type(4)));

__device__ __forceinline__ float sigm(float x) { return 1.0f / (1.0f + __expf(-x)); }
__device__ __forceinline__ float tanh_(float x) { return 1.0f - 2.0f / (1.0f + __expf(2.0f * x)); }

// x [B=32][L=700][42] f32  ->  xT [t][b][64] f16 (zero-padded 42->64)
__global__ __launch_bounds__(256) void transpose_x(const float* __restrict__ x,
                                                   f16* __restrict__ xT) {
    const int t = blockIdx.x;
    const int b = threadIdx.x >> 3;
    const int kc = (threadIdx.x & 7) * 8;
    #pragma unroll
    for (int e = 0; e < 8; ++e) {
        int k = kc + e;
        float v = (k < 42) ? x[((size_t)b * SEQL + t) * 42 + k] : 0.f;
        xT[(size_t)t * 2048 + b * 64 + k] = (f16)v;
    }
}

// ---------------------------------------------------------------------------
// Persistent LSTM layer, weight-stationary MFMA, fenceless L3-deposit sync
// (R14 structure). h published via RETURNING u32 atomic_fetch_add into
// pre-zeroed fresh t-indexed addresses (performed at L3 when vmcnt drains);
// loop-top __syncthreads then arrival RMW; consumers poll counters and read
// fresh addresses with plain loads. No cache-maintenance fences anywhere.
// R16 edit vs R14 (ONE change): DIRECT per-thread deposit -- gate threads
// (tid<256, 4 waves) pair adjacent j via __shfl_xor(.,32) into a u32 and
// deposit straight from registers. Deletes the 3rd __syncthreads + lds_h
// gather + wave0 funnel; deposit issue is 4 waves wide instead of 1.
// 8 waves/block: (tile = wid>>2, kw = wid&3); tile = 16 rows (4j x 4gates
// interleaved) x 32 batch; TPB=2 tiles; 4-way K-split reduced in LDS.
// LAYER 0: 200 blocks (100/dir); A = x-proj (K=64), B = Whh (K=800).
// LAYER 1: 200 mains + 10 logits blocks; A = Wih1 (K=1600 cached h1 reads),
//          B = Whh (K=800 reads of hh deposits); logits blocks consume hh
//          one step behind, write-once per-dir f16 logF/logR.
// ---------------------------------------------------------------------------
template <int LAYER>
__global__ __launch_bounds__(512) void lstm_phase(
    const float* __restrict__ Wih_f, const float* __restrict__ Wih_r,
    const float* __restrict__ Whh_f, const float* __restrict__ Whh_r,
    const float* __restrict__ bias_f, const float* __restrict__ bias_r,
    const f16* __restrict__ xT,
    f16* __restrict__ h1,
    f16* __restrict__ hh,
    f16* __restrict__ logF, f16* __restrict__ logR,
    const float* __restrict__ Wlin,
    unsigned* __restrict__ bar)
{
    constexpr int TPB   = 2;
    constexpr int BPD   = 100;
    constexpr int NMAIN = 200;
    constexpr int MAXA  = (LAYER == 0) ? 2 : 13;
    constexpr int MAXB  = 7;
    constexpr int GSIZE = (LAYER == 0) ? 100 : 105;
    constexpr int SMAX  = (LAYER == 0) ? 699 : 700;

    __shared__ float lds_part[8][2][16][16];
    __shared__ float lds_pre[TPB][16][32];
    __shared__ float lds_c[TPB][4][32];

    const int bid = blockIdx.x, tid = threadIdx.x;
    const int lane = tid & 63, wid = tid >> 6;
    const bool is_main = (LAYER == 0) || (bid < NMAIN);

    int dir, tb = 0;
    if (is_main) { dir = bid / BPD; tb = bid % BPD; }
    else         { dir = (bid - NMAIN) / 5; }
    unsigned* grp   = bar + ((LAYER == 0 ? 0 : 2) + dir) * 512;
    unsigned* myctr = grp + (bid & 7) * 64;

    const int tile_sel = wid >> 2, kw = wid & 3;
    const int row_local = lane & 15;
    const int kg8 = (lane >> 4) * 8;

    int cntA, offA;
    if constexpr (LAYER == 0) { cntA = (kw == 0) ? 2 : 0; offA = 0; }
    else { cntA = (kw < 2) ? 13 : 12; offA = (kw < 2) ? kw * 13 : 26 + (kw - 2) * 12; }
    const int cntB = (kw == 0) ? 7 : 6;
    const int offB = (kw == 0) ? 0 : 7 + (kw - 1) * 6;

    f16x8 aregA[MAXA];
    f16x8 aregB[MAXB];
    float biasreg[2] = {0.f, 0.f};

    if (is_main) {
        const int gate = row_local >> 2, jl = row_local & 3;
        const int jtile = tb * TPB + tile_sel;
        const int grow = gate * HID + jtile * 4 + jl;
        const float* Wih = dir ? Wih_r : Wih_f;
        const float* Whh = dir ? Whh_r : Whh_f;

        #pragma unroll
        for (int fi = 0; fi < MAXA; ++fi) {
            f16x8 a{};
            if (fi < cntA) {
                int kf = offA + fi;
                if constexpr (LAYER == 0) {
                    int k0 = kf * 32 + kg8;
                    #pragma unroll
                    for (int e = 0; e < 8; ++e)
                        a[e] = (f16)((k0 + e < 42) ? Wih[(size_t)grow * 42 + k0 + e] : 0.f);
                } else {
                    const float* p = Wih + (size_t)grow * TWOH + kf * 32 + kg8;
                    #pragma unroll
                    for (int e = 0; e < 8; ++e) a[e] = (f16)p[e];
                }
            }
            aregA[fi] = a;
        }
        #pragma unroll
        for (int fi = 0; fi < MAXB; ++fi) {
            f16x8 a{};
            if (fi < cntB) {
                const float* p = Whh + (size_t)grow * HID + (offB + fi) * 32 + kg8;
                #pragma unroll
                for (int e = 0; e < 8; ++e) a[e] = (f16)p[e];
            }
            aregB[fi] = a;
        }
        const float* bias = dir ? bias_r : bias_f;
        #pragma unroll
        for (int i = 0; i < 2; ++i) {
            int idx = tid + i * 512;
            int row = (idx >> 5) & 15, tile = idx >> 9;
            biasreg[i] = bias[(row >> 2) * HID + (tb * TPB + tile) * 4 + (row & 3)];
        }
        if (tid < TPB * 128) {
            int tile = tid >> 7, jl_ = (tid >> 5) & 3, b = tid & 31;
            lds_c[tile][jl_][b] = 0.f;
        }
    }
    __syncthreads();

    for (int s = 0; s <= SMAX; ++s) {
        const int t = dir ? (SEQL - 1 - s) : s;
        const bool do_comp = is_main && (LAYER == 0 || s < SEQL);

        __syncthreads();   // vmcnt(0): returning deposits PERFORMED at L3 pre-signal
        if (tid == 0)
            __hip_atomic_fetch_add(myctr, 1u, __ATOMIC_RELAXED, __HIP_MEMORY_SCOPE_AGENT);

        // ---- overlapped with other blocks' arrival: input projection ----
        f32x4 acc2[2];
        #pragma unroll
        for (int bt = 0; bt < 2; ++bt) acc2[bt] = {0.f, 0.f, 0.f, 0.f};
        if (do_comp) {
            const f16* srcin = (LAYER == 0) ? (xT + (size_t)t * 2048)
                                            : (h1 + (size_t)t * 51200);
            #pragma unroll
            for (int bt = 0; bt < 2; ++bt) {
                const int bcol = bt * 16 + row_local;
                #pragma unroll
                for (int fi = 0; fi < MAXA; ++fi) {
                    if (fi < cntA) {
                        int kf = offA + fi;
                        const f16x8* p = (LAYER == 0)
                            ? (const f16x8*)(srcin + (size_t)bcol * 64 + kf * 32 + kg8)
                            : (const f16x8*)(srcin + (size_t)bcol * TWOH + kf * 32 + kg8);
                        acc2[bt] = __builtin_amdgcn_mfma_f32_16x16x32_f16(aregA[fi], *p, acc2[bt], 0, 0, 0);
                    }
                }
            }
        }

        {
            // poll: lanes 0-7 read the 8 sub-counter lines in parallel,
            // shfl-reduce + broadcast; loads below are control-dependent on c
            const unsigned tgt = (unsigned)GSIZE * (unsigned)(s + 1);
            unsigned c;
            for (;;) {
                unsigned v = 0;
                if (lane < 8)
                    v = __hip_atomic_load(grp + lane * 64, __ATOMIC_RELAXED, __HIP_MEMORY_SCOPE_AGENT);
                v += __shfl_xor(v, 1);
                v += __shfl_xor(v, 2);
                v += __shfl_xor(v, 4);
                c = __shfl(v, 0);
                if (c >= tgt) break;
                __builtin_amdgcn_s_sleep(1);
            }
            if (c == 0xFFFFFFFFu) return;   // never taken: pins loads after poll
            // no acquire fence: all communicated reads below hit FRESH addresses
        }

        // ---- recurrence + finalize ----
        if (do_comp) {
            if (s > 0) {
                const int tprev = dir ? t + 1 : t - 1;
                const f16* srcrec = (LAYER == 0)
                    ? (h1 + (size_t)tprev * 51200 + dir * HID)
                    : (hh + ((size_t)(tprev * 2 + dir) * 32) * 800);
                #pragma unroll
                for (int bt = 0; bt < 2; ++bt) {
                    const int bcol = bt * 16 + row_local;
                    #pragma unroll
                    for (int fi = 0; fi < MAXB; ++fi) {
                        if (fi < cntB) {
                            int kf = offB + fi;
                            const f16x8* p = (LAYER == 0)
                                ? (const f16x8*)(srcrec + (size_t)bcol * TWOH + kf * 32 + kg8)
                                : (const f16x8*)(srcrec + (size_t)bcol * HID + kf * 32 + kg8);
                            acc2[bt] = __builtin_amdgcn_mfma_f32_16x16x32_f16(aregB[fi], *p, acc2[bt], 0, 0, 0);
                        }
                    }
                }
            }
            #pragma unroll
            for (int bt = 0; bt < 2; ++bt)
                #pragma unroll
                for (int r = 0; r < 4; ++r)
                    lds_part[wid][bt][(lane >> 4) * 4 + r][row_local] = acc2[bt][r];
        }
        __syncthreads();   // sync1: lds_part ready
        if (do_comp) {
            #pragma unroll
            for (int i = 0; i < 2; ++i) {
                int idx = tid + i * 512;
                int b = idx & 31, row = (idx >> 5) & 15, tile = idx >> 9;
                float sum = biasreg[i];
                #pragma unroll
                for (int k2 = 0; k2 < 4; ++k2)
                    sum += lds_part[tile * 4 + k2][b >> 4][row][b & 15];
                lds_pre[tile][row][b] = sum;
            }
        }
        __syncthreads();   // sync2: lds_pre ready
        if (do_comp && tid < TPB * 128) {
            // gates + DIRECT deposit (no 3rd sync, no LDS gather):
            // thread = (tile=tid>>7, jl_=(tid>>5)&3, b=tid&31); jl_ bit0 is
            // lane bit5 -> pair (jl_, jl_^1) via __shfl_xor(.,32) in-wave.
            int tile = tid >> 7, jl_ = (tid >> 5) & 3, b = tid & 31;
            float gi = sigm(lds_pre[tile][jl_][b]);
            float gf = sigm(lds_pre[tile][4 + jl_][b]);
            float gg = tanh_(lds_pre[tile][8 + jl_][b]);
            float go = sigm(lds_pre[tile][12 + jl_][b]);
            float c2 = gf * lds_c[tile][jl_][b] + gi * gg;
            lds_c[tile][jl_][b] = c2;
            union { f16 f; unsigned short u; } q;
            q.f = (f16)(go * tanh_(c2));
            unsigned hw = q.u;
            unsigned mate = __shfl_xor(hw, 32);
            if (!(tid & 32)) {   // jl_ even: deposit u32 covering (j, j+1)
                unsigned word = hw | (mate << 16);
                int j8 = tb * 8 + tile * 4 + jl_;
                f16* dst = (LAYER == 0)
                    ? h1 + (size_t)t * 51200 + (size_t)b * TWOH + dir * HID + j8
                    : hh + ((size_t)(t * 2 + dir) * 32 + b) * 800 + j8;
                // RETURNING deposit: vmcnt tracks DATA RETURN = performed at L3.
                unsigned keep = __hip_atomic_fetch_add((unsigned*)dst, word,
                                    __ATOMIC_RELAXED, __HIP_MEMORY_SCOPE_AGENT);
                asm volatile("" : : "v"(keep));   // zero-cost keepalive
            }
        }
        // logits blocks: consume hh one step behind; WRITE-ONCE per-dir f16
        if (LAYER == 1 && !is_main && s >= 1) {
            const int lb = bid - NMAIN;
            const int tL = dir ? (SEQL - s) : (s - 1);
            const int a = (lb % 5) * 4 + (tid >> 7);
            const int b = (tid >> 2) & 31;
            const int kc = tid & 3;
            const f16* hs = hh + ((size_t)(tL * 2 + dir) * 32 + b) * 800 + kc * 200;
            const float* wsrc = Wlin + (size_t)a * TWOH + dir * HID + kc * 200;
            float acc = 0.f;
            #pragma unroll
            for (int q2 = 0; q2 < 25; ++q2) {
                f16x8 hv = ((const f16x8*)hs)[q2];
                #pragma unroll
                for (int e = 0; e < 8; ++e) acc += (float)hv[e] * wsrc[q2 * 8 + e];
            }
            acc += __shfl_xor(acc, 1);
            acc += __shfl_xor(acc, 2);
            if (kc == 0) {
                f16* dst = dir ? logR : logF;
                dst[(size_t)tL * 640 + a * 32 + b] = (f16)acc;
            }
        }
    }
}

// softmax over batch (dim=1) per (l,a); prob-weighted sin/cos -> pts [m][2][32]
__global__ __launch_bounds__(64) void softmax_pts(
    const f16* __restrict__ logF, const f16* __restrict__ logR,
    const float* __restrict__ blin,
    const float* __restrict__ alpha, float* __restrict__ pts)
{
    const int l = blockIdx.x;
    const int tid = threadIdx.x;
    const int b = tid & 31;
    float sins[3] = {0.f, 0.f, 0.f}, coss[3] = {0.f, 0.f, 0.f};
    for (int a = 0; a < ALPH; ++a) {
        size_t idx = (size_t)l * 640 + (size_t)a * 32 + b;
        float v = (float)logF[idx] + (float)logR[idx] + blin[a];
        float m = v;
        #pragma unroll
        for (int d = 16; d >= 1; d >>= 1) m = fmaxf(m, __shfl_xor(m, d));
        float e = __expf(v - m);
        float ssum = e;
        #pragma unroll
        for (int d = 16; d >= 1; d >>= 1) ssum += __shfl_xor(ssum, d);
        float pv = e / ssum;
        #pragma unroll
        for (int d = 0; d < 3; ++d) {
            float ang = alpha[a * 3 + d];
            sins[d] += pv * sinf(ang);
            coss[d] += pv * cosf(ang);
        }
    }
    if (tid < 32) {
        const float blen[3] = {145.801f, 152.326f, 132.868f};
        const float bang[3] = {2.124f, 1.941f, 2.028f};
        #pragma unroll
        for (int d = 0; d < 3; ++d) {
            float pa = 3.14159265358979323846f - bang[d];
            float rsin = blen[d] * sinf(pa);
            float sv = sins[d], cv = coss[d];
            float den = sqrtf(sv * sv + cv * cv);
            float cs, sn;
            if (den > 0.f) { cs = cv / den; sn = sv / den; }
            else           { cs = 1.f;     sn = 0.f; }
            size_t m = (size_t)(3 * l + d);
            pts[m * 64 + b]      = cs * rsin;
            pts[m * 64 + 32 + b] = sn * rsin;
        }
    }
}

// NeRF chain: 32 independent batch chains in one wave.
__global__ __launch_bounds__(64) void coords_kernel(
    const float* __restrict__ pts, float* __restrict__ out)
{
    const int tid = threadIdx.x;
    const int b = tid & 31;
    float ax = -0.70710678118654752f, ay = 1.22474487139158905f, az = 0.f;
    float bx = -1.41421356237309505f, by = 0.f, bz = 0.f;
    float cx = 0.f, cy = 0.f, cz = 0.f;
    const float blen[3] = {145.801f, 152.326f, 132.868f};
    const float bang[3] = {2.124f, 1.941f, 2.028f};
    float rcos[3], rb[3];
    #pragma unroll
    for (int d = 0; d < 3; ++d) {
        rcos[d] = blen[d] * cosf(3.14159265358979323846f - bang[d]);
        rb[d] = 1.0f / blen[d];
    }
    int j = 0;
    for (int m = 0; m < 3 * SEQL; ++m) {
        float px = rcos[j];
        float py = pts[(size_t)m * 64 + b];
        float pz = pts[(size_t)m * 64 + 32 + b];
        float ux = cx - bx, uy = cy - by, uz = cz - bz;
        float inv = (m == 0) ? rsqrtf(ux * ux + uy * uy + uz * uz + 1e-12f)
                             : rb[(j + 2) % 3];
        float vx = bx - ax, vy = by - ay, vz = bz - az;
        float nx = vy * uz - vz * uy;
        float ny = vz * ux - vx * uz;
        float nz = vx * uy - vy * ux;
        float inv2 = rsqrtf(nx * nx + ny * ny + nz * nz + 1e-12f);
        nx *= inv2; ny *= inv2; nz *= inv2;
        float mx = ny * uz - nz * uy;
        float my = nz * ux - nx * uz;
        float mz = nx * uy - ny * ux;
        float sx = px * inv, sy = py * inv;
        float ox = cx + ux * sx + mx * sy + nx * pz;
        float oy = cy + uy * sx + my * sy + ny * pz;
        float oz = cz + uz * sx + mz * sy + nz * pz;
        if (tid < 32) {
            float* o = out + ((size_t)m * 32 + b) * 3;
            o[0] = ox; o[1] = oy; o[2] = oz;
        }
        ax = bx; ay = by; az = bz;
        bx = cx; by = cy; bz = cz;
        cx = ox; cy = oy; cz = oz;
        j = (j == 2) ? 0 : j + 1;
    }
}

// ---------------------------------------------------------------------------
extern "C" void kernel_launch(void* const* d_in, const int* in_sizes, int n_in,
                              void* d_out, int out_size, void* d_ws, size_t ws_size,
                              hipStream_t stream)
{
    const float* x     = (const float*)d_in[0];
    const float* Wih0f = (const float*)d_in[1];
    const float* Whh0f = (const float*)d_in[2];
    const float* b0f   = (const float*)d_in[3];
    const float* Wih0r = (const float*)d_in[4];
    const float* Whh0r = (const float*)d_in[5];
    const float* b0r   = (const float*)d_in[6];
    const float* Wih1f = (const float*)d_in[7];
    const float* Whh1f = (const float*)d_in[8];
    const float* b1f   = (const float*)d_in[9];
    const float* Wih1r = (const float*)d_in[10];
    const float* Whh1r = (const float*)d_in[11];
    const float* b1r   = (const float*)d_in[12];
    const float* Wlin  = (const float*)d_in[13];
    const float* blin  = (const float*)d_in[14];
    const float* alpha = (const float*)d_in[15];

    // ws: [bar 8KB][h1 71.68MB][hh 71.68MB][region 2.8672MB]
    // region: xT (L0 phase, dead after) aliased in L1 phase by:
    //   logF f16 @0 (896,000) | logR f16 @896,000 (896,000) |
    //   pts f32 @1,792,000 (537,600)   (total 2,329,600 <= 2,867,200)
    const size_t needFast = 8192ull + 71680000ull + 71680000ull + 2867200ull;  // 146,235,392
    if (ws_size < needFast) return;   // proven available (R10/R13/R14 ran)

    unsigned* bar = (unsigned*)d_ws;
    f16* h1 = (f16*)((char*)d_ws + 8192);
    f16* hh = (f16*)((char*)d_ws + 8192 + 71680000ull);
    char* region = (char*)d_ws + 8192 + 2ull * 71680000ull;
    f16*   xT     = (f16*)region;
    f16*   logF   = (f16*)region;
    f16*   logR   = (f16*)(region + 896000);
    float* pts    = (float*)(region + 1792000);

    hipMemsetAsync(bar, 0, 8192, stream);
    // zero h1+hh (contiguous): deposits assume old==0
    hipMemsetAsync(h1, 0, 2ull * 71680000ull, stream);
    transpose_x<<<SEQL, 256, 0, stream>>>(x, xT);
    lstm_phase<0><<<200, 512, 0, stream>>>(
        Wih0f, Wih0r, Whh0f, Whh0r, b0f, b0r,
        xT, h1, hh, logF, logR, Wlin, bar);
    lstm_phase<1><<<210, 512, 0, stream>>>(
        Wih1f, Wih1r, Whh1f, Whh1r, b1f, b1r,
        xT, h1, hh, logF, logR, Wlin, bar);
    softmax_pts<<<SEQL, 64, 0, stream>>>(logF, logR, blin, alpha, pts);
    coords_kernel<<<1, 64, 0, stream>>>(pts, (float*)d_out);
}